// Round 1
// baseline (1231.994 us; speedup 1.0000x reference)
//
#include <hip/hip_runtime.h>

// Grid constants (padded 66^3)
#define GD   66
#define GHW  (66*66)
#define GDHW (66*66*66)
#define CI   32
#define CO   32

__device__ __forceinline__ void atomAdd(float* p, float v) {
    // native global_atomic_add_f32 on gfx950
    unsafeAtomicAdd(p, v);
}

// Particle-to-grid scatter.
// CELLCO=true : dst layout [b][cell][co]  (co contiguous -> 1 cacheline per particle-offset)
// CELLCO=false: dst layout [b][co][cell]  (direct output layout, 32 lines per particle-offset)
template<bool CELLCO>
__global__ __launch_bounds__(256) void p2g_kernel(
    const float* __restrict__ x, const float* __restrict__ pos,
    const float* __restrict__ kern, const float* __restrict__ bias,
    float* __restrict__ dst, int N, int nPairs)
{
    __shared__ float kl[9*32*32];            // one oi-plane of K: 36,864 B
    const int co   = threadIdx.x & 31;
    const int half = threadIdx.x >> 5;       // 0..7 half-waves per block
    const float bco = bias[co];
    const int halvesTotal = gridDim.x * 8;

    for (int oi = 0; oi < 3; ++oi) {
        __syncthreads();                      // protect kl across chunks
        for (int i = threadIdx.x; i < 9*32*32; i += 256)
            kl[i] = kern[oi*(9*32*32) + i];
        __syncthreads();

        for (int pp = blockIdx.x*8 + half; pp < nPairs; pp += halvesTotal) {
            const int g0 = pp*2;             // two particles per half-wave

            // x for both particles, fully register-resident (broadcast loads)
            float xr[2][32];
            #pragma unroll
            for (int p = 0; p < 2; ++p) {
                const float4* xp = (const float4*)(x + (size_t)(g0+p)*CI);
                #pragma unroll
                for (int i = 0; i < 8; ++i) {
                    float4 v = xp[i];
                    xr[p][4*i+0]=v.x; xr[p][4*i+1]=v.y; xr[p][4*i+2]=v.z; xr[p][4*i+3]=v.w;
                }
            }

            float wxo[2], wy[2][3], wz[2][3];
            int cb[2], bsel[2];
            #pragma unroll
            for (int p = 0; p < 2; ++p) {
                const int gp = g0 + p;
                float px = pos[gp*3+0]*64.f, py = pos[gp*3+1]*64.f, pz = pos[gp*3+2]*64.f;
                int bx = (int)px, by = (int)py, bz = (int)pz;
                float fx = px - bx - 0.5f, fy = py - by - 0.5f, fz = pz - bz - 0.5f;
                float a0 = 0.5f*(0.5f-fx)*(0.5f-fx);
                float a1 = 0.75f - fx*fx;
                float a2 = 0.5f*(0.5f+fx)*(0.5f+fx);
                wxo[p] = (oi==0) ? a0 : ((oi==1) ? a1 : a2);
                wy[p][0]=0.5f*(0.5f-fy)*(0.5f-fy); wy[p][1]=0.75f-fy*fy; wy[p][2]=0.5f*(0.5f+fy)*(0.5f+fy);
                wz[p][0]=0.5f*(0.5f-fz)*(0.5f-fz); wz[p][1]=0.75f-fz*fz; wz[p][2]=0.5f*(0.5f+fz)*(0.5f+fz);
                cb[p]   = (bx+oi)*GHW + by*GD + bz;   // cell index for this oi plane, oj=ok=0
                bsel[p] = (gp >= N) ? 1 : 0;          // batch
            }

            #pragma unroll
            for (int oj = 0; oj < 3; ++oj) {
                #pragma unroll
                for (int ok = 0; ok < 3; ++ok) {
                    const float* kc = kl + (oj*3+ok)*1024;
                    float y0 = bco, y1 = bco;
                    #pragma unroll
                    for (int ci = 0; ci < 32; ++ci) {
                        float kv = kc[ci*32 + co];    // 32 lanes -> 32 banks; 2-way bcast across halves (free)
                        y0 += xr[0][ci]*kv;
                        y1 += xr[1][ci]*kv;
                    }
                    {
                        int cell = cb[0] + oj*GD + ok;
                        float w  = wxo[0]*wy[0][oj]*wz[0][ok];
                        size_t a = CELLCO ? (((size_t)bsel[0]*GDHW + cell)*32 + (size_t)co)
                                          : (((size_t)(bsel[0]*32 + co))*GDHW + (size_t)cell);
                        atomAdd(dst + a, w*y0);
                    }
                    {
                        int cell = cb[1] + oj*GD + ok;
                        float w  = wxo[1]*wy[1][oj]*wz[1][ok];
                        size_t a = CELLCO ? (((size_t)bsel[1]*GDHW + cell)*32 + (size_t)co)
                                          : (((size_t)(bsel[1]*32 + co))*GDHW + (size_t)cell);
                        atomAdd(dst + a, w*y1);
                    }
                }
            }
        }
    }
}

// Transpose ws[b][cell][co] -> out[b][co][cell], tiled 32x32 through LDS.
__global__ __launch_bounds__(256) void transp_kernel(
    const float* __restrict__ ws, float* __restrict__ out)
{
    __shared__ float tile[32][33];
    const int b     = blockIdx.y;
    const int cell0 = blockIdx.x * 32;
    const int n     = min(32, GDHW - cell0);

    const float* src = ws + ((size_t)b*GDHW + cell0)*32;
    for (int e = threadIdx.x; e < n*32; e += 256)
        tile[e>>5][e&31] = src[e];          // coalesced read, row write (no conflict)
    __syncthreads();
    for (int e = threadIdx.x; e < 32*32; e += 256) {
        int c  = e >> 5;    // co
        int cl = e & 31;    // cell within tile
        if (cl < n)
            out[((size_t)(b*32 + c))*GDHW + cell0 + cl] = tile[cl][c];  // coalesced write, col read stride 33
    }
}

extern "C" void kernel_launch(void* const* d_in, const int* in_sizes, int n_in,
                              void* d_out, int out_size, void* d_ws, size_t ws_size,
                              hipStream_t stream) {
    const float* x    = (const float*)d_in[0];
    const float* pos  = (const float*)d_in[1];
    const float* kern = (const float*)d_in[2];
    const float* bias = (const float*)d_in[3];
    float* out = (float*)d_out;

    const int N  = in_sizes[0] / (2*CI);   // B*N*Ci / (B*Ci)
    const int BN = 2*N;
    const int nPairs = (BN + 1) / 2;

    const size_t wsNeed = (size_t)2 * GDHW * CO * sizeof(float);  // 73.6 MB

    if (ws_size >= wsNeed) {
        float* ws = (float*)d_ws;
        hipMemsetAsync(ws, 0, wsNeed, stream);
        p2g_kernel<true><<<dim3(2048), dim3(256), 0, stream>>>(x, pos, kern, bias, ws, N, nPairs);
        transp_kernel<<<dim3((GDHW + 31)/32, 2), dim3(256), 0, stream>>>(ws, out);
    } else {
        hipMemsetAsync(out, 0, (size_t)out_size * sizeof(float), stream);
        p2g_kernel<false><<<dim3(2048), dim3(256), 0, stream>>>(x, pos, kern, bias, out, N, nPairs);
    }
}